// Round 12
// baseline (2104.012 us; speedup 1.0000x reference)
//
#include <hip/hip_runtime.h>
#include <stdint.h>

// IntegratedNCA: 64 NCA steps. B=8, CH=16, H=W=96, HID=128, WDIM=128.
// R12: TWO steps fused per kernel (32 pair-kernels + final). Per 16x8 out
// tile: stage X_s on 22x14 (halo-3, NHWC float4), phase A = full MLP
// thread=pixel on 20x12 (240 px, no reduction), life_s in LDS, phase B =
// split-2 MLP on 16x8. Ring recompute 1.44x, but per-step fixed cost
// (barrier drains, weight sweep, launch) halves and Y_s stays in LDS.
// R7/R9/R10/R11 showed occupancy/reg-blocking/vectorization don't move the
// ~15us/kernel fixed floor -- fewer kernels is the remaining lever.
//
// PRNG: JAX threefry, jax_threefry_partitionable=True (green R2/R5-R11):
//   split: key[i]  = threefry2x32(0,42, 0, i)   (host-side, passed as args)
//   bits : bits[p] = o0^o1, (o0,o1)=threefry2x32(key, 0, p); uniform<0.5 <=> bits>>31==0

#define CHN 16
#define HIDN 128
#define WD 128
#define NB 8
#define NH 96
#define NW 96
#define NSTEPS 64
#define TW 16
#define TH 8
#define PLANE (NH*NW)          // 9216
#define TILES_X (NW/TW)        // 6
#define TILES_Y (NH/TH)        // 12
#define TPI (TILES_X*TILES_Y)  // 72
#define NBLK (NB*TPI)          // 576
#define NT 256
// regions (out tile 16w x 8h):
#define AR 12                  // phase-A rows   (gh = th0-2+ar)
#define AC 20                  // phase-A cols   (gw = tw0-2+ac)
#define SR 14                  // staged X_s rows (gh = th0-3+i)
#define SC 22                  // staged X_s cols (gw = tw0-3+j)
#define BR 10                  // X_{s+1} rows   (gh = th0-1+br)
#define BC 18                  // X_{s+1} cols   (gw = tw0-1+bc)
#define PF 20                  // floats per pixel in LDS (16 + pad)
#define NSF4 (SR*SC*4)         // 1232 staged float4s

__host__ __device__ __forceinline__ uint32_t rotl(uint32_t v, int d){ return (v<<d)|(v>>(32-d)); }

__host__ __device__ __forceinline__ void threefry2x32(uint32_t k0, uint32_t k1,
                                                      uint32_t x0, uint32_t x1,
                                                      uint32_t &o0, uint32_t &o1){
  uint32_t k2 = k0 ^ k1 ^ 0x1BD11BDAu;
  x0 += k0; x1 += k1;
  x0 += x1; x1 = rotl(x1,13); x1 ^= x0;
  x0 += x1; x1 = rotl(x1,15); x1 ^= x0;
  x0 += x1; x1 = rotl(x1,26); x1 ^= x0;
  x0 += x1; x1 = rotl(x1, 6); x1 ^= x0;
  x0 += k1; x1 += k2 + 1u;
  x0 += x1; x1 = rotl(x1,17); x1 ^= x0;
  x0 += x1; x1 = rotl(x1,29); x1 ^= x0;
  x0 += x1; x1 = rotl(x1,16); x1 ^= x0;
  x0 += x1; x1 = rotl(x1,24); x1 ^= x0;
  x0 += k2; x1 += k0 + 2u;
  x0 += x1; x1 = rotl(x1,13); x1 ^= x0;
  x0 += x1; x1 = rotl(x1,15); x1 ^= x0;
  x0 += x1; x1 = rotl(x1,26); x1 ^= x0;
  x0 += x1; x1 = rotl(x1, 6); x1 ^= x0;
  x0 += k0; x1 += k1 + 3u;
  x0 += x1; x1 = rotl(x1,17); x1 ^= x0;
  x0 += x1; x1 = rotl(x1,29); x1 ^= x0;
  x0 += x1; x1 = rotl(x1,16); x1 ^= x0;
  x0 += x1; x1 = rotl(x1,24); x1 ^= x0;
  x0 += k1; x1 += k2 + 4u;
  x0 += x1; x1 = rotl(x1,13); x1 ^= x0;
  x0 += x1; x1 = rotl(x1,15); x1 ^= x0;
  x0 += x1; x1 = rotl(x1,26); x1 ^= x0;
  x0 += x1; x1 = rotl(x1, 6); x1 ^= x0;
  x0 += k2; x1 += k0 + 5u;
  o0 = x0; o1 = x1;
}

__global__ __launch_bounds__(256) void nca_pre(
    const float* __restrict__ w, const float* __restrict__ W1,
    const float* __restrict__ b1, const float* __restrict__ W2,
    float* __restrict__ w1eff, float* __restrict__ w2t, float* __restrict__ c1)
{
  const int b = blockIdx.x, t = threadIdx.x;
  if (b == 0){
    for (int idx = t; idx < HIDN*32; idx += 256){
      int n = idx >> 5, k = idx & 31;
      float v;
      if (k < 16) v = W1[n*176 + k];
      else { int cc = k - 16; v = W1[n*176 + 16 + 2*cc] + W1[n*176 + 17 + 2*cc]; }
      w1eff[idx] = v;
    }
    for (int idx = t; idx < HIDN*CHN; idx += 256){
      int n = idx >> 4, cc = idx & 15;
      w2t[idx] = W2[cc*HIDN + n];
    }
  }
  if (t < HIDN){
    float s = b1[t];
    const float* wrow = W1 + t*176 + 48;
    const float* wb = w + b*WD;
    #pragma unroll 8
    for (int k = 0; k < WD; ++k) s = fmaf(wrow[k], wb[k], s);
    c1[b*HIDN + t] = s;
  }
}

// full MLP for one pixel given xc[16], pc[16]; acc[16] out. units [n0,n1).
__device__ __forceinline__ void mlp_px(const float* __restrict__ w1eff,
                                       const float* __restrict__ w2t,
                                       const float* __restrict__ c1b,
                                       int n0, int n1,
                                       const float* xc, const float* pc, float* acc){
  #pragma unroll
  for (int i = 0; i < CHN; ++i) acc[i] = 0.f;
  #pragma unroll 4
  for (int n = n0; n < n1; ++n){
    const float* wr = w1eff + (n << 5);
    float h0 = c1b[n], h1 = 0.f, h2 = 0.f, h3 = 0.f;
    #pragma unroll
    for (int k = 0; k < 8; ++k){
      h0 = fmaf(xc[k],   wr[k],    h0);
      h1 = fmaf(xc[k+8], wr[k+8],  h1);
      h2 = fmaf(pc[k],   wr[k+16], h2);
      h3 = fmaf(pc[k+8], wr[k+24], h3);
    }
    float hv = fmaxf((h0+h1)+(h2+h3), 0.f);
    const float* w2r = w2t + (n << 4);
    #pragma unroll
    for (int cc = 0; cc < CHN; ++cc) acc[cc] = fmaf(hv, w2r[cc], acc[cc]);
  }
}

// perception from LDS tile (PF-float pixels); center at (rr,cc) row/col coords
// of the given array (reads rr-1..rr+1, cc-1..cc+1).
#define PERCEIVE(arr, COLS, rr, cc, xc, pc) do {                               \
  _Pragma("unroll")                                                            \
  for (int k4 = 0; k4 < 4; ++k4){                                              \
    float4 v = *(const float4*)&arr[(((rr))*(COLS)+(cc))*PF + k4*4];           \
    xc[k4*4+0]=v.x; xc[k4*4+1]=v.y; xc[k4*4+2]=v.z; xc[k4*4+3]=v.w;            \
  }                                                                            \
  _Pragma("unroll")                                                            \
  for (int k4 = 0; k4 < 2; ++k4){                                              \
    float4 a = *(const float4*)&arr[(((rr)-1)*(COLS)+(cc)+1)*PF + k4*4];       \
    float4 b0= *(const float4*)&arr[(((rr)-1)*(COLS)+(cc)-1)*PF + k4*4];       \
    float4 d = *(const float4*)&arr[(((rr)  )*(COLS)+(cc)+1)*PF + k4*4];       \
    float4 e = *(const float4*)&arr[(((rr)  )*(COLS)+(cc)-1)*PF + k4*4];       \
    float4 f = *(const float4*)&arr[(((rr)+1)*(COLS)+(cc)+1)*PF + k4*4];       \
    float4 g = *(const float4*)&arr[(((rr)+1)*(COLS)+(cc)-1)*PF + k4*4];       \
    pc[k4*4+0]=(a.x-b0.x)+2.f*(d.x-e.x)+(f.x-g.x);                             \
    pc[k4*4+1]=(a.y-b0.y)+2.f*(d.y-e.y)+(f.y-g.y);                             \
    pc[k4*4+2]=(a.z-b0.z)+2.f*(d.z-e.z)+(f.z-g.z);                             \
    pc[k4*4+3]=(a.w-b0.w)+2.f*(d.w-e.w)+(f.w-g.w);                             \
  }                                                                            \
  _Pragma("unroll")                                                            \
  for (int k4 = 2; k4 < 4; ++k4){                                              \
    float4 a = *(const float4*)&arr[(((rr)+1)*(COLS)+(cc)-1)*PF + k4*4];       \
    float4 b0= *(const float4*)&arr[(((rr)-1)*(COLS)+(cc)-1)*PF + k4*4];       \
    float4 d = *(const float4*)&arr[(((rr)+1)*(COLS)+(cc)  )*PF + k4*4];       \
    float4 e = *(const float4*)&arr[(((rr)-1)*(COLS)+(cc)  )*PF + k4*4];       \
    float4 f = *(const float4*)&arr[(((rr)+1)*(COLS)+(cc)+1)*PF + k4*4];       \
    float4 g = *(const float4*)&arr[(((rr)-1)*(COLS)+(cc)+1)*PF + k4*4];       \
    pc[k4*4+0]=(a.x-b0.x)+2.f*(d.x-e.x)+(f.x-g.x);                             \
    pc[k4*4+1]=(a.y-b0.y)+2.f*(d.y-e.y)+(f.y-g.y);                             \
    pc[k4*4+2]=(a.z-b0.z)+2.f*(d.z-e.z)+(f.z-g.z);                             \
    pc[k4*4+3]=(a.w-b0.w)+2.f*(d.w-e.w)+(f.w-g.w);                             \
  }                                                                            \
} while(0)

// One fused PAIR of NCA steps (s=2p, s+1=2p+1). 576 blocks x 256 thr.
template<bool FIRST>
__global__ __launch_bounds__(NT, 3) void nca_pair(
    const float* __restrict__ Xin,          // x (NCHW) if FIRST, else Y_{s-1} (NHWC)
    const unsigned char* __restrict__ Mp,   // M_{s-1} (ignored if FIRST)
    const float* __restrict__ w1eff, const float* __restrict__ w2t,
    const float* __restrict__ c1,
    uint32_t k0a, uint32_t k1a, uint32_t k0b, uint32_t k1b,
    float* __restrict__ Yn, unsigned char* __restrict__ Mn)  // step s+1 outputs (NHWC / plane)
{
  __shared__ __align__(16) float xsA[SR*SC*PF];   // 24640 B; red[16][128] aliases (phase B)
  __shared__ __align__(16) float xsB[BR*BC*PF];   // 14400 B: X_{s+1}
  __shared__ float yalA[(TH+8)*(TW+8)];           //  1536 B: Y_{s-1} alpha (16x24)
  __shared__ float lifeA[SR*SC];                  //  1232 B
  __shared__ float yalS[AR*AC];                   //   960 B: Y_s alpha (12x20)
  __shared__ float lifeS[BR*BC];                  //   720 B
  float* red = xsA;                               // [16][128] = 8192 B (xsA dead in phase B)

  const int T = blockIdx.x;
  const int b = T & 7;                  // image == XCD (%8 round-robin heuristic)
  const int t = T >> 3;
  const int tw0 = (t % TILES_X)*TW, th0 = (t / TILES_X)*TH;
  const int tid = threadIdx.x;
  const float* c1b = c1 + b*HIDN;

  // ================= stage X_s on SRxSC =================
  if (FIRST){
    for (int idx = tid; idx < CHN*SR*SC; idx += NT){
      int ch = idx / (SR*SC), rem = idx % (SR*SC);
      int i = rem / SC, j = rem % SC;
      int gh = th0 - 3 + i, gw = tw0 - 3 + j;
      float v = 0.f;
      if ((unsigned)gh < NH && (unsigned)gw < NW)
        v = Xin[((b*CHN + ch)*NH + gh)*NW + gw];
      xsA[(i*SC + j)*PF + ch] = v;
    }
    __syncthreads();
  } else {
    // Y_{s-1} alpha on 16x24 (halo 4)
    #pragma unroll
    for (int ii = 0; ii < 2; ++ii){
      int idx = tid + ii*NT;
      if (idx < (TH+8)*(TW+8)){
        int i = idx / (TW+8), j = idx % (TW+8);
        int gh = th0 - 4 + i, gw = tw0 - 4 + j;
        float v = 0.f;
        if ((unsigned)gh < NH && (unsigned)gw < NW)
          v = Xin[(size_t)(b*PLANE + gh*NW + gw)*CHN + 3];
        yalA[idx] = v;
      }
    }
    // staged Y_{s-1} float4s into regs (5/thread) + M into regs (2/thread)
    float4 xr[5];
    #pragma unroll
    for (int ii = 0; ii < 5; ++ii){
      int idx = tid + ii*NT;
      float4 v = make_float4(0.f,0.f,0.f,0.f);
      if (idx < NSF4){
        int px = idx >> 2, k4 = idx & 3;
        int i = px / SC, j = px % SC;
        int gh = th0 - 3 + i, gw = tw0 - 3 + j;
        if ((unsigned)gh < NH && (unsigned)gw < NW)
          v = *(const float4*)(Xin + (size_t)(b*PLANE + gh*NW + gw)*CHN + k4*4);
      }
      xr[ii] = v;
    }
    unsigned char mreg[2] = {0,0};
    #pragma unroll
    for (int ii = 0; ii < 2; ++ii){
      int idx = tid + ii*NT;
      if (idx < SR*SC){
        int i = idx / SC, j = idx % SC;
        int gh = th0 - 3 + i, gw = tw0 - 3 + j;
        if ((unsigned)gh < NH && (unsigned)gw < NW)
          mreg[ii] = Mp[b*PLANE + gh*NW + gw];
      }
    }
    __syncthreads();
    // life_{s-1} on SRxSC
    #pragma unroll
    for (int ii = 0; ii < 2; ++ii){
      int idx = tid + ii*NT;
      if (idx < SR*SC){
        int i = idx / SC, j = idx % SC;
        float mx = yalA[(i)*(TW+8) + j];
        #pragma unroll
        for (int dr = 0; dr < 3; ++dr)
          #pragma unroll
          for (int dc = 0; dc < 3; ++dc)
            mx = fmaxf(mx, yalA[(i+dr)*(TW+8) + (j+dc)]);
        lifeA[idx] = (mreg[ii] && (mx > 0.1f)) ? 1.f : 0.f;
      }
    }
    __syncthreads();
    // X_s = Y_{s-1} * life_{s-1}
    #pragma unroll
    for (int ii = 0; ii < 5; ++ii){
      int idx = tid + ii*NT;
      if (idx < NSF4){
        int px = idx >> 2, k4 = idx & 3;
        float lf = lifeA[px];
        float4 v = xr[ii];
        v.x *= lf; v.y *= lf; v.z *= lf; v.w *= lf;
        *(float4*)&xsA[px*PF + k4*4] = v;
      }
    }
    __syncthreads();
  }

  // ================= phase A: step s, thread = pixel (240 px) =================
  if (tid < AR*AC){
    const int ar = tid / AC, ac = tid % AC;
    const int R = 1 + ar, C = 1 + ac;
    const int gh = th0 - 2 + ar, gw = tw0 - 2 + ac;
    float xc[CHN], pc[CHN], acc[CHN];
    PERCEIVE(xsA, SC, R, C, xc, pc);
    mlp_px(w1eff, w2t, c1b, 0, HIDN, xc, pc, acc);
    float y[CHN];
    if ((unsigned)gh < NH && (unsigned)gw < NW){
      uint32_t o0, o1;
      threefry2x32(k0a, k1a, 0u, (uint32_t)(b*PLANE + gh*NW + gw), o0, o1);
      float uf = ((((o0 ^ o1) >> 31) == 0u) && (xc[3] > 0.1f)) ? 1.f : 0.f;
      #pragma unroll
      for (int cc = 0; cc < CHN; ++cc) y[cc] = fmaf(acc[cc], uf, xc[cc]);
    } else {
      #pragma unroll
      for (int cc = 0; cc < CHN; ++cc) y[cc] = 0.f;
    }
    yalS[tid] = y[3];
    if (ar >= 1 && ar < 1+BR && ac >= 1 && ac < 1+BC){
      float* dst = &xsB[((ar-1)*BC + (ac-1))*PF];
      #pragma unroll
      for (int k4 = 0; k4 < 4; ++k4)
        *(float4*)(dst + k4*4) = make_float4(y[k4*4], y[k4*4+1], y[k4*4+2], y[k4*4+3]);
    }
  }
  __syncthreads();

  // ================= life_s on BRxBC =================
  if (tid < BR*BC){
    const int br = tid / BC, bc = tid % BC;
    // pre_life(X_s alpha): window xsA rows 1+br..3+br, cols 1+bc..3+bc
    float mxX = xsA[((1+br)*SC + (1+bc))*PF + 3];
    #pragma unroll
    for (int dr = 0; dr < 3; ++dr)
      #pragma unroll
      for (int dc = 0; dc < 3; ++dc)
        mxX = fmaxf(mxX, xsA[((1+br+dr)*SC + (1+bc+dc))*PF + 3]);
    // living(Y_s alpha): window yalS rows br..br+2, cols bc..bc+2
    float mxY = yalS[br*AC + bc];
    #pragma unroll
    for (int dr = 0; dr < 3; ++dr)
      #pragma unroll
      for (int dc = 0; dc < 3; ++dc)
        mxY = fmaxf(mxY, yalS[(br+dr)*AC + (bc+dc)]);
    lifeS[tid] = ((mxX > 0.1f) && (mxY > 0.1f)) ? 1.f : 0.f;
  }
  __syncthreads();

  // ================= X_{s+1} = Y_s * life_s (in place) =================
  #pragma unroll
  for (int ii = 0; ii < 3; ++ii){
    int idx = tid + ii*NT;
    if (idx < BR*BC*4){
      int px = idx >> 2, k4 = idx & 3;
      float lf = lifeS[px];
      float4 v = *(const float4*)&xsB[px*PF + k4*4];
      v.x *= lf; v.y *= lf; v.z *= lf; v.w *= lf;
      *(float4*)&xsB[px*PF + k4*4] = v;
    }
  }
  __syncthreads();

  // ================= phase B: step s+1, 128 px x split-2 =================
  {
    const int px = tid & 127;
    const int h  = tid >> 7;            // 0: waves 0-1, 1: waves 2-3 (wave-uniform)
    const int c = px & 15, r = px >> 4;
    const int gh = th0 + r, gw = tw0 + c;
    const int pos = b*PLANE + gh*NW + gw;
    float xc[CHN], pc[CHN], acc[CHN];
    PERCEIVE(xsB, BC, (1+r), (1+c), xc, pc);
    const int nbase = __builtin_amdgcn_readfirstlane(h) << 6;
    mlp_px(w1eff, w2t, c1b, nbase, nbase+64, xc, pc, acc);
    if (h){
      #pragma unroll
      for (int cc = 0; cc < CHN; ++cc) red[cc*128 + px] = acc[cc];
      // M_{s+1} = pre_life(X_{s+1} alpha): window xsB rows r..r+2, cols c..c+2
      float mx = xsB[((1+r)*BC + (1+c))*PF + 3];
      #pragma unroll
      for (int dr = 0; dr < 3; ++dr)
        #pragma unroll
        for (int dc = 0; dc < 3; ++dc)
          mx = fmaxf(mx, xsB[((r+dr)*BC + (c+dc))*PF + 3]);
      Mn[pos] = (mx > 0.1f) ? (unsigned char)1 : (unsigned char)0;
    }
    __syncthreads();
    if (!h){
      uint32_t o0, o1;
      threefry2x32(k0b, k1b, 0u, (uint32_t)pos, o0, o1);
      float uf = ((((o0 ^ o1) >> 31) == 0u) && (xc[3] > 0.1f)) ? 1.f : 0.f;
      float* dst = Yn + (size_t)pos*CHN;
      #pragma unroll
      for (int k4 = 0; k4 < 4; ++k4){
        float4 o = make_float4(
          fmaf(acc[k4*4+0] + red[(k4*4+0)*128 + px], uf, xc[k4*4+0]),
          fmaf(acc[k4*4+1] + red[(k4*4+1)*128 + px], uf, xc[k4*4+1]),
          fmaf(acc[k4*4+2] + red[(k4*4+2)*128 + px], uf, xc[k4*4+2]),
          fmaf(acc[k4*4+3] + red[(k4*4+3)*128 + px], uf, xc[k4*4+3]));
        *(float4*)(dst + k4*4) = o;
      }
    }
  }
}

// Final: out (NCHW) = Y_63 (NHWC) * (M_63 & living(Y_63 alpha)); 16x8 tiles.
__global__ __launch_bounds__(256) void nca_final(
    const float* __restrict__ Yp, const unsigned char* __restrict__ Mp,
    float* __restrict__ out)
{
  __shared__ float ya[(TH+4)*(TW+4)];  // 12x20
  __shared__ float lifes[TH*TW];
  const int T = blockIdx.x;
  const int b = T & 7;
  const int t = T >> 3;
  const int tw0 = (t % TILES_X)*TW, th0 = (t / TILES_X)*TH;
  const int tid = threadIdx.x;
  if (tid < (TH+4)*(TW+4)){
    int i = tid / (TW+4), j = tid % (TW+4);
    int gh = th0 - 2 + i, gw = tw0 - 2 + j;
    float v = 0.f;
    if ((unsigned)gh < NH && (unsigned)gw < NW)
      v = Yp[(size_t)(b*PLANE + gh*NW + gw)*CHN + 3];
    ya[tid] = v;
  }
  __syncthreads();
  if (tid < TH*TW){
    int i = tid >> 4, j = tid & 15;
    float mx = ya[(i+2)*(TW+4) + (j+2)];
    #pragma unroll
    for (int dr = 0; dr < 3; ++dr)
      #pragma unroll
      for (int dc = 0; dc < 3; ++dc)
        mx = fmaxf(mx, ya[(i+1+dr)*(TW+4) + (j+1+dc)]);
    lifes[tid] = (Mp[b*PLANE + (th0+i)*NW + (tw0+j)] && (mx > 0.1f)) ? 1.f : 0.f;
  }
  __syncthreads();
  for (int idx = tid; idx < CHN*TH*TW; idx += 256){
    int ch = idx >> 7, p = idx & 127;
    int i = p >> 4, j = p & 15;
    int pos = b*PLANE + (th0+i)*NW + (tw0+j);
    out[((b*CHN + ch)*NH + th0 + i)*NW + tw0 + j] = Yp[(size_t)pos*CHN + ch] * lifes[p];
  }
}

extern "C" void kernel_launch(void* const* d_in, const int* in_sizes, int n_in,
                              void* d_out, int out_size, void* d_ws, size_t ws_size,
                              hipStream_t stream) {
  const float* x  = (const float*)d_in[0];
  const float* w  = (const float*)d_in[1];
  // d_in[2] = sobel (hard-coded), d_in[6] = steps (=64, hard-coded)
  const float* W1 = (const float*)d_in[3];
  const float* b1 = (const float*)d_in[4];
  const float* W2 = (const float*)d_in[5];
  float* out = (float*)d_out;
  char* ws = (char*)d_ws;

  size_t off = 0;
  float*    w1eff = (float*)(ws + off);    off += (size_t)HIDN*32*4;
  float*    w2t   = (float*)(ws + off);    off += (size_t)HIDN*CHN*4;
  float*    c1    = (float*)(ws + off);    off += (size_t)NB*HIDN*4;
  float*    Yb0   = (float*)(ws + off);    off += (size_t)NB*CHN*PLANE*4;  // NHWC
  float*    Yb1   = (float*)(ws + off);    off += (size_t)NB*CHN*PLANE*4;  // NHWC
  unsigned char* Mb0 = (unsigned char*)(ws + off); off += (size_t)NB*PLANE;
  unsigned char* Mb1 = (unsigned char*)(ws + off); off += (size_t)NB*PLANE;
  (void)ws_size; (void)in_sizes; (void)n_in; (void)out_size;

  // step keys are input-independent constants: compute on host, pass as args
  uint32_t k0[NSTEPS], k1[NSTEPS];
  for (int s = 0; s < NSTEPS; ++s) threefry2x32(0u, 42u, 0u, (uint32_t)s, k0[s], k1[s]);

  nca_pre<<<dim3(NB), dim3(256), 0, stream>>>(w, W1, b1, W2, w1eff, w2t, c1);

  // 32 fused pairs: pair p does steps 2p, 2p+1; out buffer = p&1 ? Yb1 : Yb0
  nca_pair<true><<<dim3(NBLK), dim3(NT), 0, stream>>>(
      x, Mb1 /*unused*/, w1eff, w2t, c1,
      k0[0], k1[0], k0[1], k1[1], Yb0, Mb0);
  for (int p = 1; p < NSTEPS/2; ++p){
    const float* Yp = (p & 1) ? Yb0 : Yb1;
    float*       Yn = (p & 1) ? Yb1 : Yb0;
    const unsigned char* Mq = (p & 1) ? Mb0 : Mb1;
    unsigned char*       Mw = (p & 1) ? Mb1 : Mb0;
    nca_pair<false><<<dim3(NBLK), dim3(NT), 0, stream>>>(
        Yp, Mq, w1eff, w2t, c1,
        k0[2*p], k1[2*p], k0[2*p+1], k1[2*p+1], Yn, Mw);
  }
  // p=31 (odd) wrote Yb1/Mb1
  nca_final<<<dim3(NBLK), dim3(256), 0, stream>>>(Yb1, Mb1, out);
}

// Round 13
// 1415.630 us; speedup vs baseline: 1.4863x; 1.4863x over previous
//
#include <hip/hip_runtime.h>
#include <stdint.h>

// IntegratedNCA: 64 NCA steps. B=8, CH=16, H=W=96, HID=128, WDIM=128.
// Multi-launch (per-step kernel = the global sync). Phase B (life masking)
// fused into the NEXT step's staging: X_s = Y_{s-1} * life_{s-1} in LDS.
//
// R13 = R8 (champion: 1152 blocks x 256 thr, 16x4 NCHW tiles, split-4,
// image%8 XCD pinning, single Y read) + PACKED-FP32 MLP: v_pk_fma_f32 via
// <2 x float> ext vectors. w1p[n] holds (k,k+8) pairs so one VOP3P does 2
// fmas; 2nd layer packed over channel pairs. Halves MLP VALU issue (the
// dominant per-CU work term -- R12 proved time scales with work, not
// kernel count).
//
// PRNG: JAX threefry, jax_threefry_partitionable=True (green R2/R5-R12):
//   split: key[i]  = threefry2x32(0,42, 0, i)   (host-side, passed as args)
//   bits : bits[p] = o0^o1, (o0,o1)=threefry2x32(key, 0, p); uniform<0.5 <=> bits>>31==0

#define CHN 16
#define HIDN 128
#define WD 128
#define NB 8
#define NH 96
#define NW 96
#define NSTEPS 64
#define TW 16
#define TH 4
#define PLANE (NH*NW)          // 9216
#define TILES_X (NW/TW)        // 6
#define TILES_Y (NH/TH)        // 24
#define TPI (TILES_X*TILES_Y)  // 144
#define NBLK (NB*TPI)          // 1152
#define HW_ (TH+2)             // 6 staged rows (halo 1)
#define WW_ (TW+2)             // 18 staged cols (halo 1)
#define XS_N (CHN*HW_*WW_)     // 1728 staged X elements
#define NT 256

typedef float v2f __attribute__((ext_vector_type(2)));

__host__ __device__ __forceinline__ uint32_t rotl(uint32_t v, int d){ return (v<<d)|(v>>(32-d)); }

__host__ __device__ __forceinline__ void threefry2x32(uint32_t k0, uint32_t k1,
                                                      uint32_t x0, uint32_t x1,
                                                      uint32_t &o0, uint32_t &o1){
  uint32_t k2 = k0 ^ k1 ^ 0x1BD11BDAu;
  x0 += k0; x1 += k1;
  x0 += x1; x1 = rotl(x1,13); x1 ^= x0;
  x0 += x1; x1 = rotl(x1,15); x1 ^= x0;
  x0 += x1; x1 = rotl(x1,26); x1 ^= x0;
  x0 += x1; x1 = rotl(x1, 6); x1 ^= x0;
  x0 += k1; x1 += k2 + 1u;
  x0 += x1; x1 = rotl(x1,17); x1 ^= x0;
  x0 += x1; x1 = rotl(x1,29); x1 ^= x0;
  x0 += x1; x1 = rotl(x1,16); x1 ^= x0;
  x0 += x1; x1 = rotl(x1,24); x1 ^= x0;
  x0 += k2; x1 += k0 + 2u;
  x0 += x1; x1 = rotl(x1,13); x1 ^= x0;
  x0 += x1; x1 = rotl(x1,15); x1 ^= x0;
  x0 += x1; x1 = rotl(x1,26); x1 ^= x0;
  x0 += x1; x1 = rotl(x1, 6); x1 ^= x0;
  x0 += k0; x1 += k1 + 3u;
  x0 += x1; x1 = rotl(x1,17); x1 ^= x0;
  x0 += x1; x1 = rotl(x1,29); x1 ^= x0;
  x0 += x1; x1 = rotl(x1,16); x1 ^= x0;
  x0 += x1; x1 = rotl(x1,24); x1 ^= x0;
  x0 += k1; x1 += k2 + 4u;
  x0 += x1; x1 = rotl(x1,13); x1 ^= x0;
  x0 += x1; x1 = rotl(x1,15); x1 ^= x0;
  x0 += x1; x1 = rotl(x1,26); x1 ^= x0;
  x0 += x1; x1 = rotl(x1, 6); x1 ^= x0;
  x0 += k2; x1 += k0 + 5u;
  o0 = x0; o1 = x1;
}

// Pre: w1p[128][32] in PAIR layout:
//   cols 0..15  = x-pairs:  (2k,2k+1) = (W1[n][k], W1[n][k+8]),           k=0..7
//   cols 16..31 = p-pairs:  (16+2k, 16+2k+1) = (P[k], P[k+8]),            k=0..7
//     where P[cc] = W1[n][16+2cc] + W1[n][17+2cc] (folded perception pairs)
// w2t[128][16] = W2^T (channel pairs contiguous -> packed 2nd layer),
// c1[8][128] = b1 + W1[:,48:176].w[b].
__global__ __launch_bounds__(256) void nca_pre(
    const float* __restrict__ w, const float* __restrict__ W1,
    const float* __restrict__ b1, const float* __restrict__ W2,
    float* __restrict__ w1p, float* __restrict__ w2t, float* __restrict__ c1)
{
  const int b = blockIdx.x, t = threadIdx.x;
  if (b == 0){
    for (int idx = t; idx < HIDN*32; idx += 256){
      int n = idx >> 5, k = idx & 31;
      int kp = (k & 15) >> 1, half = k & 1;
      float v;
      if (k < 16){
        int src = kp + half*8;
        v = W1[n*176 + src];
      } else {
        int cc = kp + half*8;
        v = W1[n*176 + 16 + 2*cc] + W1[n*176 + 17 + 2*cc];
      }
      w1p[idx] = v;
    }
    for (int idx = t; idx < HIDN*CHN; idx += 256){
      int n = idx >> 4, cc = idx & 15;
      w2t[idx] = W2[cc*HIDN + n];
    }
  }
  if (t < HIDN){
    float s = b1[t];
    const float* wrow = W1 + t*176 + 48;
    const float* wb = w + b*WD;
    #pragma unroll 8
    for (int k = 0; k < WD; ++k) s = fmaf(wrow[k], wb[k], s);
    c1[b*HIDN + t] = s;
  }
}

// One NCA step. Block = 16x4 pixel tile x 4 hidden quarters (256 thr, q=wave).
// FIRST: X = input x. Else: X = Yp * (Mp & living(Yp alpha)) built in LDS.
template<bool FIRST>
__global__ __launch_bounds__(NT, 6) void nca_step(
    const float* __restrict__ Xin,          // x if FIRST, else Y_{s-1}
    const unsigned char* __restrict__ Mp,   // M_{s-1} (ignored if FIRST)
    const float* __restrict__ w1p, const float* __restrict__ w2t,
    const float* __restrict__ c1,
    uint32_t key0, uint32_t key1,
    float* __restrict__ Yn, unsigned char* __restrict__ Mn)
{
  __shared__ float xs[CHN][HW_][WW_];   //  6912 B: X tile + halo 1
  __shared__ float ya[TH+4][TW+4];      //   640 B: Y alpha + halo 2 (8x20)
  __shared__ float lifes[HW_][WW_];     //   432 B
  __shared__ float red[4][CHN][64];     // 16384 B: reduction, lane=px -> 2-way (free)

  const int T = blockIdx.x;
  const int b = T & 7;                  // image == XCD (%8 round-robin heuristic)
  const int t = T >> 3;
  const int tw0 = (t % TILES_X)*TW, th0 = (t / TILES_X)*TH;
  const int tid = threadIdx.x;

  // ---- staging: single global read of Y; X held in regs while life computes
  float xreg[7];
  if (!FIRST){
    // Y alpha with halo 2 (zero-pad OOB: 0 <= 0.1 never flips the mask)
    if (tid < (TH+4)*(TW+4)){
      int hh = tid / (TW+4), ww = tid % (TW+4);
      int g2 = th0 - 2 + hh, w2 = tw0 - 2 + ww;
      float v = 0.f;
      if ((unsigned)g2 < NH && (unsigned)w2 < NW)
        v = Xin[((b*CHN + 3)*NH + g2)*NW + w2];
      ya[hh][ww] = v;
    }
  }
  #pragma unroll
  for (int i = 0; i < 7; ++i){
    int idx = tid + i*256;
    float v = 0.f;
    if (idx < XS_N){
      int ch = idx / (HW_*WW_), rem = idx % (HW_*WW_);
      int hh = rem / WW_, ww = rem % WW_;
      int g2 = th0 - 1 + hh, w2 = tw0 - 1 + ww;
      if ((unsigned)g2 < NH && (unsigned)w2 < NW)
        v = Xin[((b*CHN + ch)*NH + g2)*NW + w2];
    }
    xreg[i] = v;
  }
  if (FIRST){
    #pragma unroll
    for (int i = 0; i < 7; ++i){
      int idx = tid + i*256;
      if (idx < XS_N){
        int rem = idx % (HW_*WW_);
        xs[idx / (HW_*WW_)][rem / WW_][rem % WW_] = xreg[i];
      }
    }
  } else {
    __syncthreads();                    // ya visible
    if (tid < HW_*WW_){                 // life over tile + halo 1 (108 elems)
      int hh = tid / WW_, ww = tid % WW_;
      int g2 = th0 - 1 + hh, w2 = tw0 - 1 + ww;
      float lf = 0.f;
      if ((unsigned)g2 < NH && (unsigned)w2 < NW){
        float mx = ya[hh][ww];
        #pragma unroll
        for (int dr = 0; dr < 3; ++dr)
          #pragma unroll
          for (int dc = 0; dc < 3; ++dc)
            mx = fmaxf(mx, ya[hh+dr][ww+dc]);
        lf = (Mp[b*PLANE + g2*NW + w2] && (mx > 0.1f)) ? 1.f : 0.f;
      }
      lifes[hh][ww] = lf;
    }
    __syncthreads();                    // lifes visible
    #pragma unroll
    for (int i = 0; i < 7; ++i){
      int idx = tid + i*256;
      if (idx < XS_N){
        int ch = idx / (HW_*WW_), rem = idx % (HW_*WW_);
        int hh = rem / WW_, ww = rem % WW_;
        xs[ch][hh][ww] = xreg[i] * lifes[hh][ww];
      }
    }
  }
  __syncthreads();

  const int px = tid & 63;          // pixel in 16x4 tile
  const int q  = tid >> 6;          // hidden quarter == wave id (0..3)
  const int c = px & 15, r = px >> 4;
  const int gh = th0 + r, gw = tw0 + c;
  const int pos = b*PLANE + gh*NW + gw;

  float xc[CHN], pc[CHN];
  #pragma unroll
  for (int ch = 0; ch < CHN; ++ch) xc[ch] = xs[ch][r+1][c+1];
  // grouped conv: out ch 0..7 -> sx, 8..15 -> sy (cross-correlation)
  #pragma unroll
  for (int ch = 0; ch < 8; ++ch){
    pc[ch] =      (xs[ch][r  ][c+2] - xs[ch][r  ][c  ])
           + 2.f*(xs[ch][r+1][c+2] - xs[ch][r+1][c  ])
           +     (xs[ch][r+2][c+2] - xs[ch][r+2][c  ]);
  }
  #pragma unroll
  for (int ch = 8; ch < 16; ++ch){
    pc[ch] =      (xs[ch][r+2][c  ] - xs[ch][r  ][c  ])
           + 2.f*(xs[ch][r+2][c+1] - xs[ch][r  ][c+1])
           +     (xs[ch][r+2][c+2] - xs[ch][r  ][c+2]);
  }

  // packed operand vectors: (k, k+8) pairs
  v2f xp[8], pp[8];
  #pragma unroll
  for (int k = 0; k < 8; ++k){
    xp[k] = (v2f){xc[k], xc[k+8]};
    pp[k] = (v2f){pc[k], pc[k+8]};
  }

  v2f acc2[8];
  #pragma unroll
  for (int i = 0; i < 8; ++i) acc2[i] = (v2f){0.f, 0.f};
  // q is wave-uniform; readfirstlane keeps weight addresses provably scalar
  // (s_load path; SGPR=112 in green R5/R6/R8 kernels).
  const int nbase = __builtin_amdgcn_readfirstlane(q) << 5;
  const float* c1b = c1 + b*HIDN;

  #pragma unroll 4
  for (int nn = 0; nn < 32; ++nn){
    const int n = nbase + nn;
    const v2f* wx = (const v2f*)(w1p + (n << 5));      // 8 x-pairs then 8 p-pairs
    v2f h01 = (v2f){c1b[n], 0.f};
    v2f h23 = (v2f){0.f, 0.f};
    #pragma unroll
    for (int k = 0; k < 8; ++k){
      h01 = __builtin_elementwise_fma(xp[k], wx[k],   h01);  // v_pk_fma_f32
      h23 = __builtin_elementwise_fma(pp[k], wx[8+k], h23);
    }
    float hv = fmaxf((h01.x + h01.y) + (h23.x + h23.y), 0.f);
    v2f hvv = (v2f){hv, hv};
    const v2f* w2p = (const v2f*)(w2t + (n << 4));     // 8 channel-pairs
    #pragma unroll
    for (int cc2 = 0; cc2 < 8; ++cc2)
      acc2[cc2] = __builtin_elementwise_fma(hvv, w2p[cc2], acc2[cc2]);
  }

  #pragma unroll
  for (int cc2 = 0; cc2 < 8; ++cc2){
    red[q][2*cc2  ][px] = acc2[cc2].x;
    red[q][2*cc2+1][px] = acc2[cc2].y;
  }
  __syncthreads();

  // epilogue balanced across quarters: quarter q handles channels 4q..4q+3
  uint32_t o0, o1;
  threefry2x32(key0, key1, 0u, (uint32_t)pos, o0, o1);
  float uf = ((((o0 ^ o1) >> 31) == 0u) && (xc[3] > 0.1f)) ? 1.f : 0.f;
  #pragma unroll
  for (int cc = 0; cc < 4; ++cc){
    int ch = (q << 2) + cc;
    float v = ((red[0][ch][px] + red[1][ch][px]) +
               (red[2][ch][px] + red[3][ch][px]));
    Yn[((b*CHN + ch)*NH + gh)*NW + gw] = fmaf(v, uf, xc[ch]);
  }
  if (q == 0){  // wave-uniform branch; pre_life from (masked) X alpha
    float mx = xs[3][r][c];
    #pragma unroll
    for (int dr = 0; dr < 3; ++dr)
      #pragma unroll
      for (int dc = 0; dc < 3; ++dc)
        mx = fmaxf(mx, xs[3][r+dr][c+dc]);
    Mn[pos] = (mx > 0.1f) ? (unsigned char)1 : (unsigned char)0;
  }
}

// Final: out = Y_63 * (M_63 & living(Y_63 alpha))
__global__ __launch_bounds__(256) void nca_final(
    const float* __restrict__ Yp, const unsigned char* __restrict__ Mp,
    float* __restrict__ out)
{
  __shared__ float ya[TH+4][TW+4];     // 8x20
  __shared__ float lifes[TH][TW];
  const int T = blockIdx.x;
  const int b = T & 7;
  const int t = T >> 3;
  const int tw0 = (t % TILES_X)*TW, th0 = (t / TILES_X)*TH;
  const int tid = threadIdx.x;
  if (tid < (TH+4)*(TW+4)){
    int hh = tid / (TW+4), ww = tid % (TW+4);
    int g2 = th0 - 2 + hh, w2 = tw0 - 2 + ww;
    float v = 0.f;
    if ((unsigned)g2 < NH && (unsigned)w2 < NW)
      v = Yp[((b*CHN + 3)*NH + g2)*NW + w2];
    ya[hh][ww] = v;
  }
  __syncthreads();
  if (tid < TH*TW){
    int i = tid >> 4, j = tid & 15;
    float mx = ya[i+2][j+2];
    #pragma unroll
    for (int dr = 0; dr < 3; ++dr)
      #pragma unroll
      for (int dc = 0; dc < 3; ++dc)
        mx = fmaxf(mx, ya[i+1+dr][j+1+dc]);
    lifes[i][j] = (Mp[b*PLANE + (th0+i)*NW + (tw0+j)] && (mx > 0.1f)) ? 1.f : 0.f;
  }
  __syncthreads();
  for (int idx = tid; idx < CHN*TH*TW; idx += 256){
    int ch = idx >> 6, p = idx & 63;
    int i = p >> 4, j = p & 15;
    int o = ((b*CHN + ch)*NH + th0 + i)*NW + tw0 + j;
    out[o] = Yp[o] * lifes[i][j];
  }
}

extern "C" void kernel_launch(void* const* d_in, const int* in_sizes, int n_in,
                              void* d_out, int out_size, void* d_ws, size_t ws_size,
                              hipStream_t stream) {
  const float* x  = (const float*)d_in[0];
  const float* w  = (const float*)d_in[1];
  // d_in[2] = sobel (hard-coded), d_in[6] = steps (=64, hard-coded)
  const float* W1 = (const float*)d_in[3];
  const float* b1 = (const float*)d_in[4];
  const float* W2 = (const float*)d_in[5];
  float* out = (float*)d_out;
  char* ws = (char*)d_ws;

  size_t off = 0;
  float*    w1p   = (float*)(ws + off);    off += (size_t)HIDN*32*4;
  float*    w2t   = (float*)(ws + off);    off += (size_t)HIDN*CHN*4;
  float*    c1    = (float*)(ws + off);    off += (size_t)NB*HIDN*4;
  float*    Yb0   = (float*)(ws + off);    off += (size_t)NB*CHN*PLANE*4;
  float*    Yb1   = (float*)(ws + off);    off += (size_t)NB*CHN*PLANE*4;
  unsigned char* Mb0 = (unsigned char*)(ws + off); off += (size_t)NB*PLANE;
  unsigned char* Mb1 = (unsigned char*)(ws + off); off += (size_t)NB*PLANE;
  (void)ws_size; (void)in_sizes; (void)n_in; (void)out_size;

  // step keys are input-independent constants: compute on host, pass as args
  uint32_t k0[NSTEPS], k1[NSTEPS];
  for (int s = 0; s < NSTEPS; ++s) threefry2x32(0u, 42u, 0u, (uint32_t)s, k0[s], k1[s]);

  nca_pre<<<dim3(NB), dim3(256), 0, stream>>>(w, W1, b1, W2, w1p, w2t, c1);

  nca_step<true><<<dim3(NBLK), dim3(NT), 0, stream>>>(
      x, Mb1 /*unused*/, w1p, w2t, c1, k0[0], k1[0], Yb0, Mb0);
  for (int s = 1; s < NSTEPS; ++s){
    const float* Yp = (s & 1) ? Yb0 : Yb1;
    float*       Yn = (s & 1) ? Yb1 : Yb0;
    const unsigned char* Mq = (s & 1) ? Mb0 : Mb1;
    unsigned char*       Mn = (s & 1) ? Mb1 : Mb0;
    nca_step<false><<<dim3(NBLK), dim3(NT), 0, stream>>>(
        Yp, Mq, w1p, w2t, c1, k0[s], k1[s], Yn, Mn);
  }
  // s=63 (odd) wrote Yb1/Mb1
  nca_final<<<dim3(NBLK), dim3(256), 0, stream>>>(Yb1, Mb1, out);
}

// Round 14
// 1391.483 us; speedup vs baseline: 1.5121x; 1.0174x over previous
//
#include <hip/hip_runtime.h>
#include <stdint.h>

// IntegratedNCA: 64 NCA steps. B=8, CH=16, H=W=96, HID=128, WDIM=128.
// Multi-launch (per-step kernel = the global sync). Phase B (life masking)
// fused into the NEXT step's staging: X_s = Y_{s-1} * life_{s-1} in LDS.
//
// R14 = R13 (pk_fma MLP, champion) + R11 (channels-last NHWC state):
//  - perception: 28 ds_read_b128 instead of 112 ds_read_b32; conv in v2f
//    (natural channel pairs (2k,2k+1) share the same sx/sy filter)
//  - MLP packed with NATURAL pairs -> R8's w1eff layout read as v2f is
//    already pair-contiguous (no special interleave needed)
//  - staging: 2 coalesced float4 loads; epilogue: 1 dwordx4 per quarter
//  - threefry deduped to wave 0 (ufs in LDS); M by wave 1
// Geometry unchanged: 1152 blocks x 256 thr, 16x4 tiles, split-4, image%8
// XCD pinning (R7/R9/R10/R12 proved any other shape regresses).
//
// PRNG: JAX threefry, jax_threefry_partitionable=True (green R2/R5-R13):
//   split: key[i]  = threefry2x32(0,42, 0, i)   (host-side, passed as args)
//   bits : bits[p] = o0^o1, (o0,o1)=threefry2x32(key, 0, p); uniform<0.5 <=> bits>>31==0

#define CHN 16
#define HIDN 128
#define WD 128
#define NB 8
#define NH 96
#define NW 96
#define NSTEPS 64
#define TW 16
#define TH 4
#define PLANE (NH*NW)          // 9216
#define TILES_X (NW/TW)        // 6
#define TILES_Y (NH/TH)        // 24
#define TPI (TILES_X*TILES_Y)  // 144
#define NBLK (NB*TPI)          // 1152
#define HW_ (TH+2)             // 6 staged rows (halo 1)
#define WW_ (TW+2)             // 18 staged cols (halo 1)
#define NF4 (HW_*WW_*4)        // 432 staged float4s
#define NT 256

typedef float v2f __attribute__((ext_vector_type(2)));

__host__ __device__ __forceinline__ uint32_t rotl(uint32_t v, int d){ return (v<<d)|(v>>(32-d)); }

__host__ __device__ __forceinline__ void threefry2x32(uint32_t k0, uint32_t k1,
                                                      uint32_t x0, uint32_t x1,
                                                      uint32_t &o0, uint32_t &o1){
  uint32_t k2 = k0 ^ k1 ^ 0x1BD11BDAu;
  x0 += k0; x1 += k1;
  x0 += x1; x1 = rotl(x1,13); x1 ^= x0;
  x0 += x1; x1 = rotl(x1,15); x1 ^= x0;
  x0 += x1; x1 = rotl(x1,26); x1 ^= x0;
  x0 += x1; x1 = rotl(x1, 6); x1 ^= x0;
  x0 += k1; x1 += k2 + 1u;
  x0 += x1; x1 = rotl(x1,17); x1 ^= x0;
  x0 += x1; x1 = rotl(x1,29); x1 ^= x0;
  x0 += x1; x1 = rotl(x1,16); x1 ^= x0;
  x0 += x1; x1 = rotl(x1,24); x1 ^= x0;
  x0 += k2; x1 += k0 + 2u;
  x0 += x1; x1 = rotl(x1,13); x1 ^= x0;
  x0 += x1; x1 = rotl(x1,15); x1 ^= x0;
  x0 += x1; x1 = rotl(x1,26); x1 ^= x0;
  x0 += x1; x1 = rotl(x1, 6); x1 ^= x0;
  x0 += k0; x1 += k1 + 3u;
  x0 += x1; x1 = rotl(x1,17); x1 ^= x0;
  x0 += x1; x1 = rotl(x1,29); x1 ^= x0;
  x0 += x1; x1 = rotl(x1,16); x1 ^= x0;
  x0 += x1; x1 = rotl(x1,24); x1 ^= x0;
  x0 += k1; x1 += k2 + 4u;
  x0 += x1; x1 = rotl(x1,13); x1 ^= x0;
  x0 += x1; x1 = rotl(x1,15); x1 ^= x0;
  x0 += x1; x1 = rotl(x1,26); x1 ^= x0;
  x0 += x1; x1 = rotl(x1, 6); x1 ^= x0;
  x0 += k2; x1 += k0 + 5u;
  o0 = x0; o1 = x1;
}

// Pre: w1eff[128][32] NATURAL layout (cols 0..15 = W1[:, :16]; cols 16..31 =
// folded perception pairs P[cc] = W1[:,16+2cc]+W1[:,17+2cc]) -- v2f-readable.
// w2t[128][16] = W2^T, c1[8][128] = b1 + W1[:,48:176].w[b].
__global__ __launch_bounds__(256) void nca_pre(
    const float* __restrict__ w, const float* __restrict__ W1,
    const float* __restrict__ b1, const float* __restrict__ W2,
    float* __restrict__ w1eff, float* __restrict__ w2t, float* __restrict__ c1)
{
  const int b = blockIdx.x, t = threadIdx.x;
  if (b == 0){
    for (int idx = t; idx < HIDN*32; idx += 256){
      int n = idx >> 5, k = idx & 31;
      float v;
      if (k < 16) v = W1[n*176 + k];
      else { int cc = k - 16; v = W1[n*176 + 16 + 2*cc] + W1[n*176 + 17 + 2*cc]; }
      w1eff[idx] = v;
    }
    for (int idx = t; idx < HIDN*CHN; idx += 256){
      int n = idx >> 4, cc = idx & 15;
      w2t[idx] = W2[cc*HIDN + n];
    }
  }
  if (t < HIDN){
    float s = b1[t];
    const float* wrow = W1 + t*176 + 48;
    const float* wb = w + b*WD;
    #pragma unroll 8
    for (int k = 0; k < WD; ++k) s = fmaf(wrow[k], wb[k], s);
    c1[b*HIDN + t] = s;
  }
}

// One NCA step. Block = 16x4 pixel tile x 4 hidden quarters (256 thr, q=wave).
// FIRST: X = input x (NCHW). Else: X = Yp*(Mp & living(Yp alpha)), Yp NHWC.
template<bool FIRST>
__global__ __launch_bounds__(NT, 4) void nca_step(
    const float* __restrict__ Xin,          // x (NCHW) if FIRST, else Y_{s-1} (NHWC)
    const unsigned char* __restrict__ Mp,   // M_{s-1} (ignored if FIRST)
    const float* __restrict__ w1eff, const float* __restrict__ w2t,
    const float* __restrict__ c1,
    uint32_t key0, uint32_t key1,
    float* __restrict__ Yn, unsigned char* __restrict__ Mn)  // Yn NHWC
{
  __shared__ float xs[HW_][WW_][20];    //  8640 B: X tile+halo1, NHWC, pad 20
  __shared__ float ya[TH+4][TW+4];      //   640 B: Y alpha + halo 2 (8x20)
  __shared__ float lifes[HW_][WW_];     //   432 B
  __shared__ float ufs[64];             //   256 B: update factor per px
  __shared__ float red[4][CHN][64];     // 16384 B: partials, lane=px -> 2-way (free)

  const int T = blockIdx.x;
  const int b = T & 7;                  // image == XCD (%8 round-robin heuristic)
  const int t = T >> 3;
  const int tw0 = (t % TILES_X)*TW, th0 = (t / TILES_X)*TH;
  const int tid = threadIdx.x;

  if (FIRST){
    // one-time: scalar stage from NCHW x into NHWC LDS
    for (int idx = tid; idx < CHN*HW_*WW_; idx += NT){
      int ch = idx / (HW_*WW_), rem = idx % (HW_*WW_);
      int hh = rem / WW_, ww = rem % WW_;
      int g2 = th0 - 1 + hh, w2 = tw0 - 1 + ww;
      float v = 0.f;
      if ((unsigned)g2 < NH && (unsigned)w2 < NW)
        v = Xin[((b*CHN + ch)*NH + g2)*NW + w2];
      xs[hh][ww][ch] = v;
    }
  } else {
    // Y alpha + halo 2 (zero-pad OOB: 0 <= 0.1 never flips the mask)
    if (tid < (TH+4)*(TW+4)){
      int hh = tid / (TW+4), ww = tid % (TW+4);
      int g2 = th0 - 2 + hh, w2 = tw0 - 2 + ww;
      float v = 0.f;
      if ((unsigned)g2 < NH && (unsigned)w2 < NW)
        v = Xin[(size_t)(b*PLANE + g2*NW + w2)*CHN + 3];
      ya[hh][ww] = v;
    }
    // coalesced float4 staging of Y tile+halo1 into regs
    float4 xr[2];
    #pragma unroll
    for (int i = 0; i < 2; ++i){
      int idx = tid + i*NT;
      float4 v = make_float4(0.f,0.f,0.f,0.f);
      if (idx < NF4){
        int hh = idx / (WW_*4);
        int rem = idx % (WW_*4);
        int ww = rem >> 2, k4 = rem & 3;
        int g2 = th0 - 1 + hh, w2 = tw0 - 1 + ww;
        if ((unsigned)g2 < NH && (unsigned)w2 < NW)
          v = *(const float4*)(Xin + (size_t)(b*PLANE + g2*NW + w2)*CHN + k4*4);
      }
      xr[i] = v;
    }
    __syncthreads();                    // ya visible
    if (tid < HW_*WW_){                 // life over tile + halo 1 (108 elems)
      int hh = tid / WW_, ww = tid % WW_;
      int g2 = th0 - 1 + hh, w2 = tw0 - 1 + ww;
      float lf = 0.f;
      if ((unsigned)g2 < NH && (unsigned)w2 < NW){
        float mx = ya[hh][ww];
        #pragma unroll
        for (int dr = 0; dr < 3; ++dr)
          #pragma unroll
          for (int dc = 0; dc < 3; ++dc)
            mx = fmaxf(mx, ya[hh+dr][ww+dc]);
        lf = (Mp[b*PLANE + g2*NW + w2] && (mx > 0.1f)) ? 1.f : 0.f;
      }
      lifes[hh][ww] = lf;
    }
    __syncthreads();                    // lifes visible
    #pragma unroll
    for (int i = 0; i < 2; ++i){
      int idx = tid + i*NT;
      if (idx < NF4){
        int hh = idx / (WW_*4);
        int rem = idx % (WW_*4);
        int ww = rem >> 2, k4 = rem & 3;
        float lf = lifes[hh][ww];
        float4 v = xr[i];
        v.x *= lf; v.y *= lf; v.z *= lf; v.w *= lf;
        *(float4*)&xs[hh][ww][k4*4] = v;   // 16B-aligned (80B row stride)
      }
    }
  }
  __syncthreads();

  const int px = tid & 63;          // pixel in 16x4 tile
  const int q  = tid >> 6;          // hidden quarter == wave id (0..3)
  const int c = px & 15, r = px >> 4;
  const int gh = th0 + r, gw = tw0 + c;
  const int pos = b*PLANE + gh*NW + gw;

  // perception via b128 LDS reads; conv arithmetic in v2f (natural pairs
  // (2k,2k+1) share the same filter: k4<2 -> sx, k4>=2 -> sy)
  #define LD4(dr,dc,k4) (*(const float4*)&xs[r+(dr)][c+(dc)][(k4)*4])
  const v2f two = (v2f){2.f, 2.f};
  float4 xc4[4];
  v2f xp[8], pp[8];
  #pragma unroll
  for (int k4 = 0; k4 < 4; ++k4){
    xc4[k4] = LD4(1,1,k4);
    xp[2*k4]   = (v2f){xc4[k4].x, xc4[k4].y};
    xp[2*k4+1] = (v2f){xc4[k4].z, xc4[k4].w};
  }
  #pragma unroll
  for (int k4 = 0; k4 < 2; ++k4){      // sx -> ch 0..7
    float4 a = LD4(0,2,k4), b0 = LD4(0,0,k4);
    float4 d = LD4(1,2,k4), e = LD4(1,0,k4);
    float4 f = LD4(2,2,k4), g = LD4(2,0,k4);
    v2f a0 = (v2f){a.x,a.y}, a1 = (v2f){a.z,a.w};
    v2f b0v= (v2f){b0.x,b0.y},b1v= (v2f){b0.z,b0.w};
    v2f d0 = (v2f){d.x,d.y}, d1 = (v2f){d.z,d.w};
    v2f e0 = (v2f){e.x,e.y}, e1 = (v2f){e.z,e.w};
    v2f f0 = (v2f){f.x,f.y}, f1 = (v2f){f.z,f.w};
    v2f g0 = (v2f){g.x,g.y}, g1 = (v2f){g.z,g.w};
    pp[2*k4]   = (a0-b0v) + two*(d0-e0) + (f0-g0);
    pp[2*k4+1] = (a1-b1v) + two*(d1-e1) + (f1-g1);
  }
  #pragma unroll
  for (int k4 = 2; k4 < 4; ++k4){      // sy -> ch 8..15
    float4 a = LD4(2,0,k4), b0 = LD4(0,0,k4);
    float4 d = LD4(2,1,k4), e = LD4(0,1,k4);
    float4 f = LD4(2,2,k4), g = LD4(0,2,k4);
    v2f a0 = (v2f){a.x,a.y}, a1 = (v2f){a.z,a.w};
    v2f b0v= (v2f){b0.x,b0.y},b1v= (v2f){b0.z,b0.w};
    v2f d0 = (v2f){d.x,d.y}, d1 = (v2f){d.z,d.w};
    v2f e0 = (v2f){e.x,e.y}, e1 = (v2f){e.z,e.w};
    v2f f0 = (v2f){f.x,f.y}, f1 = (v2f){f.z,f.w};
    v2f g0 = (v2f){g.x,g.y}, g1 = (v2f){g.z,g.w};
    pp[2*k4]   = (a0-b0v) + two*(d0-e0) + (f0-g0);
    pp[2*k4+1] = (a1-b1v) + two*(d1-e1) + (f1-g1);
  }
  #undef LD4

  // threefry deduped to wave 0; M (pre_life of masked X alpha) by wave 1
  if (q == 0){
    uint32_t o0, o1;
    threefry2x32(key0, key1, 0u, (uint32_t)pos, o0, o1);
    ufs[px] = ((((o0 ^ o1) >> 31) == 0u) && (xc4[0].w > 0.1f)) ? 1.f : 0.f;
  } else if (q == 1){
    float mx = xs[r][c][3];
    #pragma unroll
    for (int dr = 0; dr < 3; ++dr)
      #pragma unroll
      for (int dc = 0; dc < 3; ++dc)
        mx = fmaxf(mx, xs[r+dr][c+dc][3]);
    Mn[pos] = (mx > 0.1f) ? (unsigned char)1 : (unsigned char)0;
  }

  // ---- packed MLP: 32 hidden units per quarter (natural-pair v2f weights)
  v2f acc2[8];
  #pragma unroll
  for (int i = 0; i < 8; ++i) acc2[i] = (v2f){0.f, 0.f};
  // q is wave-uniform; readfirstlane keeps weight addresses provably scalar
  // (s_load path; SGPR=112 in green R5/R6/R8/R13 kernels).
  const int nbase = __builtin_amdgcn_readfirstlane(q) << 5;
  const float* c1b = c1 + b*HIDN;

  #pragma unroll 4
  for (int nn = 0; nn < 32; ++nn){
    const int n = nbase + nn;
    const v2f* wx = (const v2f*)(w1eff + (n << 5));   // 8 x-pairs then 8 p-pairs
    v2f h01 = (v2f){c1b[n], 0.f};
    v2f h23 = (v2f){0.f, 0.f};
    #pragma unroll
    for (int k = 0; k < 8; ++k){
      h01 = __builtin_elementwise_fma(xp[k], wx[k],   h01);  // v_pk_fma_f32
      h23 = __builtin_elementwise_fma(pp[k], wx[8+k], h23);
    }
    float hv = fmaxf((h01.x + h01.y) + (h23.x + h23.y), 0.f);
    v2f hvv = (v2f){hv, hv};
    const v2f* w2p = (const v2f*)(w2t + (n << 4));    // 8 channel-pairs
    #pragma unroll
    for (int cc2 = 0; cc2 < 8; ++cc2)
      acc2[cc2] = __builtin_elementwise_fma(hvv, w2p[cc2], acc2[cc2]);
  }

  #pragma unroll
  for (int cc2 = 0; cc2 < 8; ++cc2){
    red[q][2*cc2  ][px] = acc2[cc2].x;
    red[q][2*cc2+1][px] = acc2[cc2].y;
  }
  __syncthreads();

  // epilogue: quarter q writes channels 4q..4q+3 as ONE float4 (NHWC)
  {
    float uf = ufs[px];
    int ch = q << 2;
    float v0 = ((red[0][ch+0][px] + red[1][ch+0][px]) + (red[2][ch+0][px] + red[3][ch+0][px]));
    float v1 = ((red[0][ch+1][px] + red[1][ch+1][px]) + (red[2][ch+1][px] + red[3][ch+1][px]));
    float v2 = ((red[0][ch+2][px] + red[1][ch+2][px]) + (red[2][ch+2][px] + red[3][ch+2][px]));
    float v3 = ((red[0][ch+3][px] + red[1][ch+3][px]) + (red[2][ch+3][px] + red[3][ch+3][px]));
    float4 o = make_float4(fmaf(v0, uf, xc4[q].x), fmaf(v1, uf, xc4[q].y),
                           fmaf(v2, uf, xc4[q].z), fmaf(v3, uf, xc4[q].w));
    *(float4*)(Yn + (size_t)pos*CHN + q*4) = o;
  }
}

// Final: out (NCHW) = Y_63 (NHWC) * (M_63 & living(Y_63 alpha))
__global__ __launch_bounds__(256) void nca_final(
    const float* __restrict__ Yp, const unsigned char* __restrict__ Mp,
    float* __restrict__ out)
{
  __shared__ float ya[TH+4][TW+4];     // 8x20
  __shared__ float lifes[TH][TW];
  const int T = blockIdx.x;
  const int b = T & 7;
  const int t = T >> 3;
  const int tw0 = (t % TILES_X)*TW, th0 = (t / TILES_X)*TH;
  const int tid = threadIdx.x;
  if (tid < (TH+4)*(TW+4)){
    int hh = tid / (TW+4), ww = tid % (TW+4);
    int g2 = th0 - 2 + hh, w2 = tw0 - 2 + ww;
    float v = 0.f;
    if ((unsigned)g2 < NH && (unsigned)w2 < NW)
      v = Yp[(size_t)(b*PLANE + g2*NW + w2)*CHN + 3];
    ya[hh][ww] = v;
  }
  __syncthreads();
  if (tid < TH*TW){
    int i = tid >> 4, j = tid & 15;
    float mx = ya[i+2][j+2];
    #pragma unroll
    for (int dr = 0; dr < 3; ++dr)
      #pragma unroll
      for (int dc = 0; dc < 3; ++dc)
        mx = fmaxf(mx, ya[i+1+dr][j+1+dc]);
    lifes[i][j] = (Mp[b*PLANE + (th0+i)*NW + (tw0+j)] && (mx > 0.1f)) ? 1.f : 0.f;
  }
  __syncthreads();
  for (int idx = tid; idx < CHN*TH*TW; idx += 256){
    int ch = idx >> 6, p = idx & 63;
    int i = p >> 4, j = p & 15;
    int pos = b*PLANE + (th0+i)*NW + (tw0+j);
    out[((b*CHN + ch)*NH + th0 + i)*NW + tw0 + j] = Yp[(size_t)pos*CHN + ch] * lifes[i][j];
  }
}

extern "C" void kernel_launch(void* const* d_in, const int* in_sizes, int n_in,
                              void* d_out, int out_size, void* d_ws, size_t ws_size,
                              hipStream_t stream) {
  const float* x  = (const float*)d_in[0];
  const float* w  = (const float*)d_in[1];
  // d_in[2] = sobel (hard-coded), d_in[6] = steps (=64, hard-coded)
  const float* W1 = (const float*)d_in[3];
  const float* b1 = (const float*)d_in[4];
  const float* W2 = (const float*)d_in[5];
  float* out = (float*)d_out;
  char* ws = (char*)d_ws;

  size_t off = 0;
  float*    w1eff = (float*)(ws + off);    off += (size_t)HIDN*32*4;
  float*    w2t   = (float*)(ws + off);    off += (size_t)HIDN*CHN*4;
  float*    c1    = (float*)(ws + off);    off += (size_t)NB*HIDN*4;
  float*    Yb0   = (float*)(ws + off);    off += (size_t)NB*CHN*PLANE*4;  // NHWC
  float*    Yb1   = (float*)(ws + off);    off += (size_t)NB*CHN*PLANE*4;  // NHWC
  unsigned char* Mb0 = (unsigned char*)(ws + off); off += (size_t)NB*PLANE;
  unsigned char* Mb1 = (unsigned char*)(ws + off); off += (size_t)NB*PLANE;
  (void)ws_size; (void)in_sizes; (void)n_in; (void)out_size;

  // step keys are input-independent constants: compute on host, pass as args
  uint32_t k0[NSTEPS], k1[NSTEPS];
  for (int s = 0; s < NSTEPS; ++s) threefry2x32(0u, 42u, 0u, (uint32_t)s, k0[s], k1[s]);

  nca_pre<<<dim3(NB), dim3(256), 0, stream>>>(w, W1, b1, W2, w1eff, w2t, c1);

  nca_step<true><<<dim3(NBLK), dim3(NT), 0, stream>>>(
      x, Mb1 /*unused*/, w1eff, w2t, c1, k0[0], k1[0], Yb0, Mb0);
  for (int s = 1; s < NSTEPS; ++s){
    const float* Yp = (s & 1) ? Yb0 : Yb1;
    float*       Yn = (s & 1) ? Yb1 : Yb0;
    const unsigned char* Mq = (s & 1) ? Mb0 : Mb1;
    unsigned char*       Mn = (s & 1) ? Mb1 : Mb0;
    nca_step<false><<<dim3(NBLK), dim3(NT), 0, stream>>>(
        Yp, Mq, w1eff, w2t, c1, k0[s], k1[s], Yn, Mn);
  }
  // s=63 (odd) wrote Yb1/Mb1
  nca_final<<<dim3(NBLK), dim3(256), 0, stream>>>(Yb1, Mb1, out);
}